// Round 6
// baseline (160.894 us; speedup 1.0000x reference)
//
#include <hip/hip_runtime.h>
#include <hip/hip_bf16.h>

#define N_NODES 50000
#define N_EDGES 800000
#define NF 64            // IN_F == OUT_F == 64
#define BUCK_SHIFT 5
#define BUCK_SIZE 32     // rows per bucket
#define NBUK ((N_NODES + BUCK_SIZE - 1) / BUCK_SIZE)  // 1563
#define CAP 768          // slots per bucket (mean 512, sd ~23 -> +11 sigma)
#define CHUNK 4096       // edges per binning block
#define BIN_BLOCKS ((N_EDGES + CHUNK - 1) / CHUNK)    // 196
#define GEMM_BLOCKS 64
#define PROD_BLOCK 1024

// ---------------- kernel 1: fused producer ----------------
// blocks [0, BIN_BLOCKS): bin 4096 edges each into fixed-capacity buckets.
//   16 waves/block (vs 4 before) to hide the scattered-store latency; edges
//   held in registers across phases (single global read).
// blocks [BIN_BLOCKS, +GEMM_BLOCKS): support = bf16(x @ W), one wave per row,
//   W column in 64 VGPRs, wave-uniform x-row scalar loads.
// Independent halves overlap on the machine instead of running serially.
__global__ __launch_bounds__(1024) void produce(
    const float* __restrict__ x, const int* __restrict__ erow,
    const int* __restrict__ ecol, const float* __restrict__ eval,
    const float* __restrict__ w, int* __restrict__ cursor,
    int2* __restrict__ stage1, __hip_bfloat16* __restrict__ support) {
  __shared__ int hist[NBUK];
  __shared__ int base[NBUK];
  __shared__ int lcur[NBUK];
  const int tid = threadIdx.x;

  if (blockIdx.x < BIN_BLOCKS) {
    // ---- binning half ----
    for (int t = tid; t < NBUK; t += PROD_BLOCK) hist[t] = 0;
    __syncthreads();

    const int e0 = blockIdx.x * CHUNK;
    const int e1 = min(e0 + CHUNK, N_EDGES);
    int r[4], c[4];
    float v[4];
    int n = 0;
    for (int e = e0 + tid; e < e1; e += PROD_BLOCK) {
      r[n] = erow[e];
      c[n] = ecol[e];
      v[n] = eval[e];
      atomicAdd(&hist[r[n] >> BUCK_SHIFT], 1);
      ++n;
    }
    __syncthreads();

    for (int t = tid; t < NBUK; t += PROD_BLOCK) {
      const int cnt = hist[t];
      base[t] = cnt ? t * CAP + atomicAdd(&cursor[t], cnt) : 0;
      lcur[t] = 0;
    }
    __syncthreads();

    for (int j = 0; j < n; ++j) {
      const int b = r[j] >> BUCK_SHIFT;
      const int ofs = atomicAdd(&lcur[b], 1);
      const int pos = base[b] + ofs;
      if (pos < (b + 1) * CAP)  // safety clamp; statistically never taken
        stage1[pos] = make_int2(((r[j] & (BUCK_SIZE - 1)) << 16) | c[j],
                                __float_as_int(v[j]));
    }
  } else {
    // ---- GEMM half ----
    const int lane = tid & 63;
    const int wave = tid >> 6;  // 0..15

    float wcol[NF];
#pragma unroll
    for (int k = 0; k < NF; ++k) wcol[k] = w[k * NF + lane];

    const int wid = (blockIdx.x - BIN_BLOCKS) * 16 + wave;  // 0..1023
    for (int row = wid; row < N_NODES; row += GEMM_BLOCKS * 16) {
      const int row_u = __builtin_amdgcn_readfirstlane(row);
      const float* xr = x + (size_t)row_u * NF;
      float a0 = 0.f, a1 = 0.f, a2 = 0.f, a3 = 0.f;
#pragma unroll
      for (int k = 0; k < NF; k += 4) {
        a0 = fmaf(xr[k + 0], wcol[k + 0], a0);
        a1 = fmaf(xr[k + 1], wcol[k + 1], a1);
        a2 = fmaf(xr[k + 2], wcol[k + 2], a2);
        a3 = fmaf(xr[k + 3], wcol[k + 3], a3);
      }
      support[(size_t)row_u * NF + lane] =
          __float2bfloat16((a0 + a1) + (a2 + a3));
    }
  }
}

// ---------------- kernel 2: fused sort-in-LDS + register SpMM ----------------
// One block per 32-row bucket. Phase A: load bucket edges into LDS, count
// per-row (int LDS atomics), 32-wide shfl scan, place a row-sorted copy in
// LDS. Phase B: each wave register-accumulates 8 rows (lane = feature),
// x4-unrolled coalesced bf16 gathers, one coalesced store per row. No f32
// atomics anywhere; 1563 blocks / 6252 waves for latency hiding.
__global__ __launch_bounds__(256) void spmm_sorted(
    const __hip_bfloat16* __restrict__ support, const int* __restrict__ cursor,
    const int2* __restrict__ stage1, const float* __restrict__ bias,
    float* __restrict__ out) {
  __shared__ int2 raw[CAP];  // 6 KB
  __shared__ int2 srt[CAP];  // 6 KB
  __shared__ int rcnt[BUCK_SIZE];
  __shared__ int rofs[BUCK_SIZE];
  __shared__ int rcur[BUCK_SIZE];
  const int b = blockIdx.x;
  const int tid = threadIdx.x;
  const int lane = tid & 63;
  const int wave = tid >> 6;

  if (tid < BUCK_SIZE) rcnt[tid] = 0;
  __syncthreads();

  int cnt = cursor[b];
  cnt = cnt > CAP ? CAP : cnt;
  const int2* eb = stage1 + (size_t)b * CAP;

  // Phase A1: load + per-row count
  for (int i = tid; i < cnt; i += 256) {
    const int2 m = eb[i];
    raw[i] = m;
    atomicAdd(&rcnt[m.x >> 16], 1);
  }
  __syncthreads();

  // Phase A2: exclusive scan of 32 counters (wave 0)
  if (tid < 64) {
    const int v = (lane < BUCK_SIZE) ? rcnt[lane] : 0;
    int sc = v;
#pragma unroll
    for (int off = 1; off < 32; off <<= 1) {
      const int up = __shfl_up(sc, off, 64);
      if (lane >= off) sc += up;
    }
    if (lane < BUCK_SIZE) {
      rofs[lane] = sc - v;
      rcur[lane] = sc - v;
    }
  }
  __syncthreads();

  // Phase A3: place row-sorted
  for (int i = tid; i < cnt; i += 256) {
    const int2 m = raw[i];
    const int p = atomicAdd(&rcur[m.x >> 16], 1);
    srt[p] = m;
  }
  __syncthreads();

  // Phase B: per-row register accumulation, 8 rows per wave
  const int row0 = b << BUCK_SHIFT;
  const float bv = bias[lane];
#pragma unroll
  for (int rr = 0; rr < 8; ++rr) {
    const int rl = wave * 8 + rr;
    const int row = row0 + rl;
    if (row >= N_NODES) break;  // wave-uniform
    const int s = __builtin_amdgcn_readfirstlane(rofs[rl]);
    const int e = __builtin_amdgcn_readfirstlane(rofs[rl] + rcnt[rl]);
    float a0 = 0.f, a1 = 0.f, a2 = 0.f, a3 = 0.f;
    int i = s;
    for (; i + 4 <= e; i += 4) {
      const int2 m0 = srt[i + 0];
      const int2 m1 = srt[i + 1];
      const int2 m2 = srt[i + 2];
      const int2 m3 = srt[i + 3];
      const float s0 = __bfloat162float(support[(size_t)(m0.x & 0xFFFF) * NF + lane]);
      const float s1 = __bfloat162float(support[(size_t)(m1.x & 0xFFFF) * NF + lane]);
      const float s2 = __bfloat162float(support[(size_t)(m2.x & 0xFFFF) * NF + lane]);
      const float s3 = __bfloat162float(support[(size_t)(m3.x & 0xFFFF) * NF + lane]);
      a0 = fmaf(__int_as_float(m0.y), s0, a0);
      a1 = fmaf(__int_as_float(m1.y), s1, a1);
      a2 = fmaf(__int_as_float(m2.y), s2, a2);
      a3 = fmaf(__int_as_float(m3.y), s3, a3);
    }
    for (; i < e; ++i) {
      const int2 m0 = srt[i];
      a0 = fmaf(__int_as_float(m0.y),
                __bfloat162float(support[(size_t)(m0.x & 0xFFFF) * NF + lane]),
                a0);
    }
    out[(size_t)row * NF + lane] = ((a0 + a1) + (a2 + a3)) + bv;
  }
}

// -------------------- launch --------------------
extern "C" void kernel_launch(void* const* d_in, const int* in_sizes, int n_in,
                              void* d_out, int out_size, void* d_ws,
                              size_t ws_size, hipStream_t stream) {
  const float* x = (const float*)d_in[0];
  const int* erow = (const int*)d_in[1];
  const int* ecol = (const int*)d_in[2];
  const float* eval = (const float*)d_in[3];
  const float* w = (const float*)d_in[4];
  const float* bias = (const float*)d_in[5];
  float* out = (float*)d_out;

  // workspace layout (16B-aligned)
  char* ws = (char*)d_ws;
  __hip_bfloat16* support = (__hip_bfloat16*)(ws);  //  6,400,000 B
  int2* stage1 = (int2*)(ws + 6400000);             //  9,603,072 B (1563*768*8)
  int* cursor = (int*)(ws + 16003072);              //      6,252 B (1563)
  // total ~16.0 MB

  hipMemsetAsync(cursor, 0, NBUK * sizeof(int), stream);

  produce<<<BIN_BLOCKS + GEMM_BLOCKS, PROD_BLOCK, 0, stream>>>(
      x, erow, ecol, eval, w, cursor, stage1, support);
  spmm_sorted<<<NBUK, 256, 0, stream>>>(support, cursor, stage1, bias, out);
}

// Round 8
// 129.689 us; speedup vs baseline: 1.2406x; 1.2406x over previous
//
#include <hip/hip_runtime.h>
#include <hip/hip_bf16.h>

#define N_NODES 50000
#define N_EDGES 800000
#define NF 64            // IN_F == OUT_F == 64
#define BUCK_SHIFT 5
#define BUCK_SIZE 32     // rows per bucket
#define NBUK ((N_NODES + BUCK_SIZE - 1) / BUCK_SIZE)  // 1563
#define CAP 768          // slots per bucket (mean 512, sd ~23 -> +11 sigma)
#define CHUNK 4096       // edges per binning block
#define BIN_BLOCKS ((N_EDGES + CHUNK - 1) / CHUNK)    // 196
#define GEMM_BLOCKS 828
#define CSTRIDE 16       // cursor padded to one bucket per 64-B line

// ---------------- kernel 1: fused producer (bin || gemm), 256 thr ----------
// blocks [0,196): round-5 binning config (4 waves -> no LDS-conflict blowup,
//   short barrier skew). Edges register-cached across phases (one global
//   read). cursor padded to 64-B stride so bucket reservations never share a
//   cache line (kills cross-XCD atomic line bouncing).
// blocks [196,1024): support = bf16(x @ W), one wave per row, W column in 64
//   VGPRs, wave-uniform x-row scalar loads. Overlaps with binning on the
//   machine (separate pipes), instead of a serial dispatch.
__global__ __launch_bounds__(256) void produce(
    const float* __restrict__ x, const int* __restrict__ erow,
    const int* __restrict__ ecol, const float* __restrict__ eval,
    const float* __restrict__ w, int* __restrict__ cursor,
    int2* __restrict__ stage1, __hip_bfloat16* __restrict__ support) {
  __shared__ int hist[NBUK];
  __shared__ int base[NBUK];
  __shared__ int lcur[NBUK];
  const int tid = threadIdx.x;
  const int lane = tid & 63;
  const int wave = tid >> 6;

  if (blockIdx.x < BIN_BLOCKS) {
    // ---- binning half ----
    for (int t = tid; t < NBUK; t += 256) hist[t] = 0;
    __syncthreads();

    const int e0 = blockIdx.x * CHUNK;
    const int e1 = min(e0 + CHUNK, N_EDGES);
    int r[16], c[16];
    float v[16];
    int n = 0;
    for (int e = e0 + tid; e < e1; e += 256) {
      r[n] = erow[e];
      c[n] = ecol[e];
      v[n] = eval[e];
      atomicAdd(&hist[r[n] >> BUCK_SHIFT], 1);
      ++n;
    }
    __syncthreads();

    for (int t = tid; t < NBUK; t += 256) {
      const int cnt = hist[t];
      base[t] = cnt ? t * CAP + atomicAdd(&cursor[t * CSTRIDE], cnt) : 0;
      lcur[t] = 0;
    }
    __syncthreads();

    for (int j = 0; j < n; ++j) {
      const int b = r[j] >> BUCK_SHIFT;
      const int ofs = atomicAdd(&lcur[b], 1);
      const int pos = base[b] + ofs;
      if (pos < (b + 1) * CAP)  // safety clamp; statistically never taken
        stage1[pos] = make_int2(((r[j] & (BUCK_SIZE - 1)) << 16) | c[j],
                                __float_as_int(v[j]));
    }
  } else {
    // ---- gemm half ----
    float wcol[NF];
#pragma unroll
    for (int k = 0; k < NF; ++k) wcol[k] = w[k * NF + lane];

    const int wid = (blockIdx.x - BIN_BLOCKS) * 4 + wave;
    const int nw = GEMM_BLOCKS * 4;  // 3312 waves
    for (int row = wid; row < N_NODES; row += nw) {
      const int row_u = __builtin_amdgcn_readfirstlane(row);
      const float* xr = x + (size_t)row_u * NF;
      float a0 = 0.f, a1 = 0.f, a2 = 0.f, a3 = 0.f;
#pragma unroll
      for (int k = 0; k < NF; k += 4) {
        a0 = fmaf(xr[k + 0], wcol[k + 0], a0);
        a1 = fmaf(xr[k + 1], wcol[k + 1], a1);
        a2 = fmaf(xr[k + 2], wcol[k + 2], a2);
        a3 = fmaf(xr[k + 3], wcol[k + 3], a3);
      }
      support[(size_t)row_u * NF + lane] =
          __float2bfloat16((a0 + a1) + (a2 + a3));
    }
  }
}

// ---------------- kernel 2: fused sort-in-LDS + register SpMM ----------------
// One block per 32-row bucket (round-5 verbatim, cursor stride updated).
__global__ __launch_bounds__(256) void spmm_sorted(
    const __hip_bfloat16* __restrict__ support, const int* __restrict__ cursor,
    const int2* __restrict__ stage1, const float* __restrict__ bias,
    float* __restrict__ out) {
  __shared__ int2 raw[CAP];  // 6 KB
  __shared__ int2 srt[CAP];  // 6 KB
  __shared__ int rcnt[BUCK_SIZE];
  __shared__ int rofs[BUCK_SIZE];
  __shared__ int rcur[BUCK_SIZE];
  const int b = blockIdx.x;
  const int tid = threadIdx.x;
  const int lane = tid & 63;
  const int wave = tid >> 6;

  if (tid < BUCK_SIZE) rcnt[tid] = 0;
  __syncthreads();

  int cnt = cursor[b * CSTRIDE];
  cnt = cnt > CAP ? CAP : cnt;
  const int2* eb = stage1 + (size_t)b * CAP;

  // A1: load + per-row count
  for (int i = tid; i < cnt; i += 256) {
    const int2 m = eb[i];
    raw[i] = m;
    atomicAdd(&rcnt[m.x >> 16], 1);
  }
  __syncthreads();

  // A2: exclusive scan of 32 counters (wave 0)
  if (tid < 64) {
    const int v = (lane < BUCK_SIZE) ? rcnt[lane] : 0;
    int sc = v;
#pragma unroll
    for (int off = 1; off < 32; off <<= 1) {
      const int up = __shfl_up(sc, off, 64);
      if (lane >= off) sc += up;
    }
    if (lane < BUCK_SIZE) {
      rofs[lane] = sc - v;
      rcur[lane] = sc - v;
    }
  }
  __syncthreads();

  // A3: place row-sorted
  for (int i = tid; i < cnt; i += 256) {
    const int2 m = raw[i];
    const int p = atomicAdd(&rcur[m.x >> 16], 1);
    srt[p] = m;
  }
  __syncthreads();

  // B: per-row register accumulation, 8 rows per wave
  const int row0 = b << BUCK_SHIFT;
  const float bv = bias[lane];
#pragma unroll
  for (int rr = 0; rr < 8; ++rr) {
    const int rl = wave * 8 + rr;
    const int row = row0 + rl;
    if (row >= N_NODES) break;  // wave-uniform
    const int s = __builtin_amdgcn_readfirstlane(rofs[rl]);
    const int e = __builtin_amdgcn_readfirstlane(rofs[rl] + rcnt[rl]);
    float a0 = 0.f, a1 = 0.f, a2 = 0.f, a3 = 0.f;
    int i = s;
    for (; i + 4 <= e; i += 4) {
      const int2 m0 = srt[i + 0];
      const int2 m1 = srt[i + 1];
      const int2 m2 = srt[i + 2];
      const int2 m3 = srt[i + 3];
      const float s0 = __bfloat162float(support[(size_t)(m0.x & 0xFFFF) * NF + lane]);
      const float s1 = __bfloat162float(support[(size_t)(m1.x & 0xFFFF) * NF + lane]);
      const float s2 = __bfloat162float(support[(size_t)(m2.x & 0xFFFF) * NF + lane]);
      const float s3 = __bfloat162float(support[(size_t)(m3.x & 0xFFFF) * NF + lane]);
      a0 = fmaf(__int_as_float(m0.y), s0, a0);
      a1 = fmaf(__int_as_float(m1.y), s1, a1);
      a2 = fmaf(__int_as_float(m2.y), s2, a2);
      a3 = fmaf(__int_as_float(m3.y), s3, a3);
    }
    for (; i < e; ++i) {
      const int2 m0 = srt[i];
      a0 = fmaf(__int_as_float(m0.y),
                __bfloat162float(support[(size_t)(m0.x & 0xFFFF) * NF + lane]),
                a0);
    }
    out[(size_t)row * NF + lane] = ((a0 + a1) + (a2 + a3)) + bv;
  }
}

// -------------------- launch --------------------
extern "C" void kernel_launch(void* const* d_in, const int* in_sizes, int n_in,
                              void* d_out, int out_size, void* d_ws,
                              size_t ws_size, hipStream_t stream) {
  const float* x = (const float*)d_in[0];
  const int* erow = (const int*)d_in[1];
  const int* ecol = (const int*)d_in[2];
  const float* eval = (const float*)d_in[3];
  const float* w = (const float*)d_in[4];
  const float* bias = (const float*)d_in[5];
  float* out = (float*)d_out;

  // workspace layout (16B-aligned)
  char* ws = (char*)d_ws;
  __hip_bfloat16* support = (__hip_bfloat16*)(ws);  //  6,400,000 B
  int2* stage1 = (int2*)(ws + 6400000);             //  9,603,072 B (1563*768*8)
  int* cursor = (int*)(ws + 16003072);              //    100,032 B (1563*16*4)
  // total ~16.1 MB

  hipMemsetAsync(cursor, 0, NBUK * CSTRIDE * sizeof(int), stream);

  produce<<<BIN_BLOCKS + GEMM_BLOCKS, 256, 0, stream>>>(
      x, erow, ecol, eval, w, cursor, stage1, support);
  spmm_sorted<<<NBUK, 256, 0, stream>>>(support, cursor, stage1, bias, out);
}